// Round 1
// 276.003 us; speedup vs baseline: 1.0840x; 1.0840x over previous
//
#include <hip/hip_runtime.h>

// CTC loss forward, T=1024, B=128, C=256, S=128, L=2S+1=257.
// One wave (64 lanes) per batch. Lane l owns odd states O[2l],O[2l+1]
// (labels y[2l],y[2l+1]) and blank states E[2l],E[2l+1]; E[128] kept
// LANE-LOCAL (only lane 63's copy is real; broadcast once at the end).
// Exp-domain recursion in FP64 with exact power-of-2 renorm every 8 steps.
//
// R2 changes (theory: serial chain was DS-permute latency-bound, ~250 of
// 360 cy/step stalled on ds_bpermute):
//  - __shfl_up(Ob,1)  -> DPP wave_shr:1 (VALU, zero-fills lane 0)
//  - __shfl(Ob,63)    -> removed (lane-local E128)
//  - renorm butterfly -> u32 hi-word max via 4 DPP rounds + readlane/s_max
//    (exponent-only, no DS, no branch; eb==0 => scale 2^1022 handles zeros)
//  - two-stage prefetch: raw f32 loaded 16 steps ahead, exp'd to f64 8
//    steps ahead, so neither HBM (~900cy) nor exp/cvt latency sits on the
//    ~110cy/step critical path.

#define CTC_C 256
#define NRDY 8    // exp'd-probability pipeline depth
#define NRAW 16   // raw-float pipeline depth (load lead = 16 steps ahead of exp)

__device__ __forceinline__ unsigned umin32(unsigned a, unsigned b) { return a < b ? a : b; }

// full-wave shift-right-by-1, lane 0 gets 0 (DPP wave_shr:1, bound_ctrl:0)
__device__ __forceinline__ double wshr1_f64(double x) {
  int lo = __double2loint(x), hi = __double2hiint(x);
  lo = __builtin_amdgcn_update_dpp(0, lo, 0x138, 0xf, 0xf, true);
  hi = __builtin_amdgcn_update_dpp(0, hi, 0x138, 0xf, 0xf, true);
  return __hiloint2double(hi, lo);
}

template <int CTRL>
__device__ __forceinline__ unsigned dppmax(unsigned v) {
  unsigned t = (unsigned)__builtin_amdgcn_update_dpp(0, (int)v, CTRL, 0xf, 0xf, true);
  return v > t ? v : t;
}

// Wave-uniform power-of-2 renorm. Positive doubles order by bit pattern, so
// the max of the high words carries the exponent of the wave max. All-VALU
// reduction: 4 DPP rounds within 16-lane rows, then readlane + scalar max.
__device__ __forceinline__ void renorm(double& Oa, double& Ob, double& Ea,
                                       double& Eb, double& E128, double& logC) {
  unsigned m =       (unsigned)__double2hiint(Oa);
  unsigned h;
  h = (unsigned)__double2hiint(Ob);   m = m > h ? m : h;
  h = (unsigned)__double2hiint(Ea);   m = m > h ? m : h;
  h = (unsigned)__double2hiint(Eb);   m = m > h ? m : h;
  h = (unsigned)__double2hiint(E128); m = m > h ? m : h;
  m = dppmax<0xB1>(m);    // quad_perm [1,0,3,2]  (xor 1)
  m = dppmax<0x4E>(m);    // quad_perm [2,3,0,1]  (xor 2)
  m = dppmax<0x141>(m);   // row_half_mirror      (combine 4<->4)
  m = dppmax<0x140>(m);   // row_mirror           (combine 8<->8): row max everywhere
  unsigned r0 = (unsigned)__builtin_amdgcn_readlane((int)m, 0);
  unsigned r1 = (unsigned)__builtin_amdgcn_readlane((int)m, 16);
  unsigned r2 = (unsigned)__builtin_amdgcn_readlane((int)m, 32);
  unsigned r3 = (unsigned)__builtin_amdgcn_readlane((int)m, 48);
  unsigned m01 = r0 > r1 ? r0 : r1;
  unsigned m23 = r2 > r3 ? r2 : r3;
  unsigned smax = m01 > m23 ? m01 : m23;
  int eb = (int)(smax >> 20);  // biased exponent of the wave max (sign bit is 0)
  // scale = 2^-(eb-1022) exactly; eb==0 (all zero/denormal) => 2^1022, still exact
  double s = __hiloint2double((int)((unsigned)(2045 - eb) << 20), 0);
  Oa *= s; Ob *= s; Ea *= s; Eb *= s; E128 *= s;
  logC += (double)(eb - 1022) * 0.6931471805599453;
}

__global__ __launch_bounds__(64)
void ctc_fwd(const float* __restrict__ lp, const int* __restrict__ y,
             const int* __restrict__ ilen, const int* __restrict__ tlen,
             float* __restrict__ out, int T, int B, int S) {
  const int b = blockIdx.x;
  const int l = threadIdx.x;            // 0..63
  const size_t rowstrideF = (size_t)B * CTC_C;       // floats between rows
  const unsigned ROWB = (unsigned)(B * CTC_C * 4);   // bytes between rows

  const int len = ilen[b];              // input length, steps t=1..len-1
  const int tl  = tlen[b];              // target length

  const int ya = y[(size_t)b * S + 2 * l];
  const int yb = y[(size_t)b * S + 2 * l + 1];
  const int yprev = __shfl_up(yb, 1);   // y[2l-1] (garbage on lane 0, masked)
  const bool skipA = (l > 0) && (ya != yprev);
  const bool skipB = (yb != ya);

  // Init (t=0)
  const float* row0 = lp + (size_t)b * CTC_C;
  const int y0 = y[(size_t)b * S];
  double Ea = (l == 0) ? (double)__expf(row0[0])  : 0.;
  double Oa = (l == 0) ? (double)__expf(row0[y0]) : 0.;
  double Eb = 0., Ob = 0., E128 = 0., logC = 0.;

  // ---- prime the two-stage prefetch pipeline ----
  float  rA[NRAW], rB[NRAW], rQ[NRAW];  // raw log-probs, row t held in slot t&15
  double eA[NRDY], eB[NRDY], eQ[NRDY];  // exp'd probs,   row t held in slot t&7

#pragma unroll
  for (int t = 1; t <= NRDY; ++t) {     // rows 1..8 ready as probabilities
    const float* r = lp + (size_t)t * rowstrideF + (size_t)b * CTC_C;
    eA[t & 7] = (double)__expf(r[ya]);
    eB[t & 7] = (double)__expf(r[yb]);
    eQ[t & 7] = (double)__expf(r[0]);
  }
#pragma unroll
  for (int t = NRDY + 1; t <= NRDY + NRAW; ++t) {  // rows 9..24 raw
    const float* r = lp + (size_t)t * rowstrideF + (size_t)b * CTC_C;
    rA[t & 15] = r[ya];
    rB[t & 15] = r[yb];
    rQ[t & 15] = r[0];
  }

  // rolling 32-bit byte offsets for future loads (row t+24 issued at step t);
  // whole tensor is T*B*C*4 = 128 MB so 32-bit offsets suffice.
  const char* base = (const char*)lp;
  const unsigned rowoff = (unsigned)b * CTC_C * 4u;
  unsigned offA = (unsigned)(NRDY + NRAW + 1) * ROWB + rowoff + 4u * (unsigned)ya;
  unsigned offB = (unsigned)(NRDY + NRAW + 1) * ROWB + rowoff + 4u * (unsigned)yb;
  unsigned offQ = (unsigned)(NRDY + NRAW + 1) * ROWB + rowoff;
  const unsigned capA = (unsigned)(T - 1) * ROWB + rowoff + 4u * (unsigned)ya;
  const unsigned capB = (unsigned)(T - 1) * ROWB + rowoff + 4u * (unsigned)yb;
  const unsigned capQ = (unsigned)(T - 1) * ROWB + rowoff;
  offA = umin32(offA, capA); offB = umin32(offB, capB); offQ = umin32(offQ, capQ);

  // One recursion step. Chunks start at t ≡ 1 (mod 16), so slot indices are
  // compile-time: step t uses ready slot (1+i)&7 and exp's raw slot (9+i)&15,
  // then reloads that raw slot with row t+24 (clamped to T-1; extra reads of
  // the last row are harmless and never consumed).
#define CTC_STEP(i_)                                                          \
  do {                                                                        \
    const int d8  = (1 + (i_)) & 7;                                           \
    const int d16 = (9 + (i_)) & 15;                                          \
    const double pa = eA[d8], pb = eB[d8], pq = eQ[d8];                       \
    eA[d8] = (double)__expf(rA[d16]);                                         \
    eB[d8] = (double)__expf(rB[d16]);                                         \
    eQ[d8] = (double)__expf(rQ[d16]);                                         \
    rA[d16] = *(const float*)(base + offA);                                   \
    rB[d16] = *(const float*)(base + offB);                                   \
    rQ[d16] = *(const float*)(base + offQ);                                   \
    offA = umin32(offA + ROWB, capA);                                         \
    offB = umin32(offB + ROWB, capB);                                         \
    offQ = umin32(offQ + ROWB, capQ);                                         \
    const double Opm1 = wshr1_f64(Ob);      /* O[2l-1], 0 on lane 0 */        \
    const double EaOp = Ea + Opm1;                                            \
    const double EbOa = Eb + Oa;                                              \
    const double tA = skipA ? EaOp : Ea;                                      \
    const double tB = skipB ? EbOa : Eb;                                      \
    const double nOa = (Oa + tA) * pa;                                        \
    const double nOb = (Ob + tB) * pb;                                        \
    Ea = EaOp * pq;                                                           \
    Eb = EbOa * pq;                                                           \
    E128 = (E128 + Ob) * pq;                /* real only on lane 63 */        \
    Oa = nOa; Ob = nOb;                                                       \
  } while (0)

  const int nsteps = len - 1;           // steps t = 1..nsteps (len >= 768)
  const int nch = nsteps >> 4;          // full 16-step chunks
  const int rem = nsteps & 15;

  for (int c = 0; c < nch; ++c) {
#pragma unroll
    for (int i = 0; i < 16; ++i) {
      CTC_STEP(i);
      if ((i & 7) == 7) renorm(Oa, Ob, Ea, Eb, E128, logC);
    }
  }
  if (rem) {                            // guarded tail chunk (wave-uniform)
#pragma unroll
    for (int i = 0; i < 16; ++i) {
      if (i < rem) {
        CTC_STEP(i);
        if ((i & 7) == 7) renorm(Oa, Ob, Ea, Eb, E128, logC);
      }
    }
  }
#undef CTC_STEP

  // Final: ll = logC + log(alpha_exp[2*tl] + alpha_exp[2*tl-1])
  double vEa = __shfl(Ea, (tl >> 1) & 63);
  double vEb = __shfl(Eb, (tl >> 1) & 63);
  double vE128 = __shfl(E128, 63);      // the one real E[128]
  double vhi = (tl == S) ? vE128 : ((tl & 1) ? vEb : vEa);
  const int s2 = tl - 1;
  double vOa = __shfl(Oa, (s2 >> 1) & 63);
  double vOb = __shfl(Ob, (s2 >> 1) & 63);
  double vlo = (s2 & 1) ? vOb : vOa;

  double sum = vhi + vlo;
  double loss;
  if (sum > 0.) {
    loss = -(logC + log(sum));
  } else {
    loss = 1e30;                        // -inf likelihood
  }
  if (!(loss < 5.0e8)) loss = 0.;       // zero_infinity (catches inf/NaN)
  float contrib = (float)(loss / (double)tl / (double)B);
  if (l == 0) atomicAdd(out, contrib);
}

extern "C" void kernel_launch(void* const* d_in, const int* in_sizes, int n_in,
                              void* d_out, int out_size, void* d_ws, size_t ws_size,
                              hipStream_t stream) {
  const float* lp   = (const float*)d_in[0];
  const int*   yy   = (const int*)d_in[1];
  const int*   ilen = (const int*)d_in[2];
  const int*   tlen = (const int*)d_in[3];
  float* out = (float*)d_out;

  int B = in_sizes[2];
  int S = in_sizes[1] / B;
  int T = in_sizes[0] / (B * CTC_C);

  hipMemsetAsync(out, 0, sizeof(float), stream);
  ctc_fwd<<<B, 64, 0, stream>>>(lp, yy, ilen, tlen, out, T, B, S);
}

// Round 3
// 258.861 us; speedup vs baseline: 1.1558x; 1.0662x over previous
//
#include <hip/hip_runtime.h>

// CTC loss forward, T=1024, B=128, C=256, S=128, L=2S+1=257.
// One wave (64 lanes) per batch. Lane l owns odd states O[2l],O[2l+1]
// (labels y[2l],y[2l+1]) and blank states E[2l],E[2l+1]; E[128] kept
// LANE-LOCAL (only lane 63's copy is real; broadcast once at the end).
// Exp-domain recursion in FP64 with exact power-of-2 renorm every 8 steps.
//
// R3: back to plain-HIP 16-deep register prefetch (R1 structure, which was
// register-resident per VGPR_Count=72), plus sched_barrier(0) per step.
// R1's residual 210cy/step stall was the machine scheduler CLUSTERING all
// 48 refill loads at the end of each unrolled 16-step block, so the first
// uses of the next block sat right behind the issues. sched_barrier(0) at
// each step boundary pins every load ~16 steps (~2000cy) ahead of its use;
// the compiler's own counted vmcnt inserts are then already satisfied.
// (R2's volatile-asm load + hand vmcnt pinning aborted at runtime — dropped.)
// Refill addressing made wave-uniform: rolling scalar row byte-offset with
// s_min clamp; per-lane voffset (b*C + label) is loop-invariant.
//
// Kept from R1 (verified, absmax 0.0): DPP wave_shr:1 neighbor shift,
// lane-local E128, exponent-only renorm via DPP-max + readlane.

#define CTC_C 256
#define DEP 16    // prefetch depth in steps; 3*DEP = 48 loads in flight

// full-wave shift-right-by-1, lane 0 gets 0 (DPP wave_shr:1, bound_ctrl:0)
__device__ __forceinline__ double wshr1_f64(double x) {
  int lo = __double2loint(x), hi = __double2hiint(x);
  lo = __builtin_amdgcn_update_dpp(0, lo, 0x138, 0xf, 0xf, true);
  hi = __builtin_amdgcn_update_dpp(0, hi, 0x138, 0xf, 0xf, true);
  return __hiloint2double(hi, lo);
}

template <int CTRL>
__device__ __forceinline__ unsigned dppmax(unsigned v) {
  unsigned t = (unsigned)__builtin_amdgcn_update_dpp(0, (int)v, CTRL, 0xf, 0xf, true);
  return v > t ? v : t;
}

// Wave-uniform power-of-2 renorm. Positive doubles order by bit pattern, so
// the max of the high words carries the exponent of the wave max. All-VALU
// reduction: 4 DPP rounds within 16-lane rows, then readlane + scalar max.
__device__ __forceinline__ void renorm(double& Oa, double& Ob, double& Ea,
                                       double& Eb, double& E128, double& logC) {
  unsigned m =       (unsigned)__double2hiint(Oa);
  unsigned h;
  h = (unsigned)__double2hiint(Ob);   m = m > h ? m : h;
  h = (unsigned)__double2hiint(Ea);   m = m > h ? m : h;
  h = (unsigned)__double2hiint(Eb);   m = m > h ? m : h;
  h = (unsigned)__double2hiint(E128); m = m > h ? m : h;
  m = dppmax<0xB1>(m);    // quad_perm [1,0,3,2]  (xor 1)
  m = dppmax<0x4E>(m);    // quad_perm [2,3,0,1]  (xor 2)
  m = dppmax<0x141>(m);   // row_half_mirror      (4<->4)
  m = dppmax<0x140>(m);   // row_mirror           (8<->8): row max everywhere
  unsigned r0 = (unsigned)__builtin_amdgcn_readlane((int)m, 0);
  unsigned r1 = (unsigned)__builtin_amdgcn_readlane((int)m, 16);
  unsigned r2 = (unsigned)__builtin_amdgcn_readlane((int)m, 32);
  unsigned r3 = (unsigned)__builtin_amdgcn_readlane((int)m, 48);
  unsigned m01 = r0 > r1 ? r0 : r1;
  unsigned m23 = r2 > r3 ? r2 : r3;
  unsigned smax = m01 > m23 ? m01 : m23;
  int eb = (int)(smax >> 20);  // biased exponent of the wave max (sign bit 0)
  // scale = 2^-(eb-1022) exactly; eb==0 (all zero) => 2^1022, still exact
  double s = __hiloint2double((int)((unsigned)(2045 - eb) << 20), 0);
  Oa *= s; Ob *= s; Ea *= s; Eb *= s; E128 *= s;
  logC += (double)(eb - 1022) * 0.6931471805599453;
}

__global__ __launch_bounds__(64)
void ctc_fwd(const float* __restrict__ lp, const int* __restrict__ y,
             const int* __restrict__ ilen, const int* __restrict__ tlen,
             float* __restrict__ out, int T, int B, int S) {
  const int b = blockIdx.x;
  const int l = threadIdx.x;            // 0..63
  const size_t rowstrideF = (size_t)B * CTC_C;       // floats between rows
  const unsigned ROWB = (unsigned)(B * CTC_C * 4);   // bytes between rows

  const int len = ilen[b];              // input length, steps t=1..len-1
  const int tl  = tlen[b];              // target length

  const int ya = y[(size_t)b * S + 2 * l];
  const int yb = y[(size_t)b * S + 2 * l + 1];
  const int yprev = __shfl_up(yb, 1);   // y[2l-1] (garbage on lane 0, masked)
  const bool skipA = (l > 0) && (ya != yprev);
  const bool skipB = (yb != ya);

  // Init (t=0)
  const float* row0 = lp + (size_t)b * CTC_C;
  const int y0 = y[(size_t)b * S];
  double Ea = (l == 0) ? (double)__expf(row0[0])  : 0.;
  double Oa = (l == 0) ? (double)__expf(row0[y0]) : 0.;
  double Eb = 0., Ob = 0., E128 = 0., logC = 0.;

  // Loop-invariant per-lane element indices within a row block
  const int fA = b * CTC_C + ya;        // gathered label A
  const int fB = b * CTC_C + yb;        // gathered label B
  const int fQ = b * CTC_C;             // blank

  // ---- prime the pipeline: rows 1..DEP, slot = t & 15 ----
  float rA[DEP], rB[DEP], rQ[DEP];
#pragma unroll
  for (int t = 1; t <= DEP; ++t) {
    const float* r = lp + (size_t)t * rowstrideF;
    rA[t & 15] = r[fA]; rB[t & 15] = r[fB]; rQ[t & 15] = r[fQ];
  }

  // Rolling WAVE-UNIFORM byte offset of the refill row (row t+DEP, clamped
  // to T-1; over-reads of the last row are never consumed). Scalar-unit math.
  const unsigned capR = (unsigned)(T - 1) * ROWB;
  unsigned uoff = (unsigned)(DEP + 1) * ROWB;   // refill row for step t=1

  // One recursion step. Chunks start at t ≡ 1 (mod 16) so slots are
  // compile-time. sched_barrier(0) at the end of each step prevents the
  // machine scheduler from clustering refill loads across steps (which in
  // R1 put all 48 issues at the block end, right behind their uses).
#define CTC_STEP(i_)                                                          \
  do {                                                                        \
    const int d = (1 + (i_)) & 15;                                            \
    const double pa = (double)__expf(rA[d]);                                  \
    const double pb = (double)__expf(rB[d]);                                  \
    const double pq = (double)__expf(rQ[d]);                                  \
    {                                                                         \
      const float* rp = (const float*)((const char*)lp + uoff);               \
      rA[d] = rp[fA]; rB[d] = rp[fB]; rQ[d] = rp[fQ];                         \
      unsigned un = uoff + ROWB;                                              \
      uoff = un < capR ? un : capR;                                           \
    }                                                                         \
    const double Opm1 = wshr1_f64(Ob);      /* O[2l-1], 0 on lane 0 */        \
    const double EaOp = Ea + Opm1;                                            \
    const double EbOa = Eb + Oa;                                              \
    const double tA = skipA ? EaOp : Ea;                                      \
    const double tB = skipB ? EbOa : Eb;                                      \
    const double nOa = (Oa + tA) * pa;                                        \
    const double nOb = (Ob + tB) * pb;                                        \
    Ea = EaOp * pq;                                                           \
    Eb = EbOa * pq;                                                           \
    E128 = (E128 + Ob) * pq;                /* real only on lane 63 */        \
    Oa = nOa; Ob = nOb;                                                       \
    __builtin_amdgcn_sched_barrier(0);                                        \
  } while (0)

  const int nsteps = len - 1;           // steps t = 1..nsteps (len >= 768)
  const int nch = nsteps >> 4;          // full 16-step chunks
  const int rem = nsteps & 15;

  for (int c = 0; c < nch; ++c) {
#pragma unroll
    for (int i = 0; i < 16; ++i) {
      CTC_STEP(i);
      if ((i & 7) == 7) renorm(Oa, Ob, Ea, Eb, E128, logC);
    }
  }
  if (rem) {                            // guarded tail chunk (wave-uniform)
#pragma unroll
    for (int i = 0; i < 16; ++i) {
      if (i < rem) {
        CTC_STEP(i);
        if ((i & 7) == 7) renorm(Oa, Ob, Ea, Eb, E128, logC);
      }
    }
  }
#undef CTC_STEP

  // Final: ll = logC + log(alpha_exp[2*tl] + alpha_exp[2*tl-1])
  double vEa = __shfl(Ea, (tl >> 1) & 63);
  double vEb = __shfl(Eb, (tl >> 1) & 63);
  double vE128 = __shfl(E128, 63);      // the one real E[128]
  double vhi = (tl == S) ? vE128 : ((tl & 1) ? vEb : vEa);
  const int s2 = tl - 1;
  double vOa = __shfl(Oa, (s2 >> 1) & 63);
  double vOb = __shfl(Ob, (s2 >> 1) & 63);
  double vlo = (s2 & 1) ? vOb : vOa;

  double sum = vhi + vlo;
  double loss;
  if (sum > 0.) {
    loss = -(logC + log(sum));
  } else {
    loss = 1e30;                        // -inf likelihood
  }
  if (!(loss < 5.0e8)) loss = 0.;       // zero_infinity (catches inf/NaN)
  float contrib = (float)(loss / (double)tl / (double)B);
  if (l == 0) atomicAdd(out, contrib);
}

extern "C" void kernel_launch(void* const* d_in, const int* in_sizes, int n_in,
                              void* d_out, int out_size, void* d_ws, size_t ws_size,
                              hipStream_t stream) {
  const float* lp   = (const float*)d_in[0];
  const int*   yy   = (const int*)d_in[1];
  const int*   ilen = (const int*)d_in[2];
  const int*   tlen = (const int*)d_in[3];
  float* out = (float*)d_out;

  int B = in_sizes[2];
  int S = in_sizes[1] / B;
  int T = in_sizes[0] / (B * CTC_C);

  hipMemsetAsync(out, 0, sizeof(float), stream);
  ctc_fwd<<<B, 64, 0, stream>>>(lp, yy, ilen, tlen, out, T, B, S);
}